// Round 3
// baseline (135.974 us; speedup 1.0000x reference)
//
#include <hip/hip_runtime.h>
#include <hip/hip_bf16.h>

typedef __attribute__((ext_vector_type(8))) short short8;   // 8 bf16 (MFMA A/B frag)
typedef __attribute__((ext_vector_type(4))) float floatx4;  // MFMA C/D frag
typedef unsigned int u32;

#define D_DIM 256
#define TCOLS 32      // B-tile width -> 3-buf LDS = 3*32*256*2 = 49152 B
#define TILES 8       // tiles per block -> 256 cols/block -> grid 32x32 = 1024 blocks
#define IDX_BITS 0x1FFFu      // 13-bit index payload (N=M=8192)
#define VAL_MASK 0xFFFFE000u  // truncated value bits (sim+2 positive -> raw bits monotone)

// ---------- helpers ----------

__device__ inline unsigned short f2bf_rne(float f) {
  u32 u = __float_as_uint(f);
  u32 r = (u + 0x7FFFu + ((u >> 16) & 1u)) >> 16;
  return (unsigned short)r;
}

__device__ inline u32 umax(u32 a, u32 b) { return a > b ? a : b; }

__device__ inline void async_ld16(const void* g, void* l) {
  __builtin_amdgcn_global_load_lds((const __attribute__((address_space(1))) void*)g,
                                   (__attribute__((address_space(3))) void*)l, 16, 0, 0);
}

// stage one 32x256 B tile: 1024 x 16B slots, XOR-swizzled source so the
// frag-read un-swizzle spreads banks. LDS dest linear (gload_lds requirement).
__device__ __forceinline__ void stage_tile(const unsigned short* __restrict__ src,
                                           unsigned short* dstb, int tid) {
#pragma unroll
  for (int c = 0; c < 4; ++c) {
    int slot = c * 256 + tid;
    int r = slot >> 5, cc = slot & 31;
    int ccg = (cc & 24) | ((cc ^ r) & 7);
    async_ld16(src + (size_t)r * D_DIM + ccg * 8, dstb + slot * 8);
  }
}

// deferred argmax epilogue for the tile whose columns start at m0.
// pay(x) = (~x)&IDX_BITS == 0x1FFF - x for x in [0,8191].
__device__ __forceinline__ void epilogue(const floatx4 (&acc)[4][2], int m0,
                                         u32 (&rbk)[16], u32 rp0,
                                         u32* __restrict__ colbest_tile,
                                         int l15, int quad) {
  u32 cb[2] = {0u, 0u};
  u32 colpay[2] = {0x1FFFu - (u32)(m0 + l15), 0x1FFFu - (u32)(m0 + 16 + l15)};
#pragma unroll
  for (int i = 0; i < 4; ++i)
#pragma unroll
    for (int r = 0; r < 4; ++r) {
      u32 rp = rp0 - (u32)(i * 16 + r);  // row payload, recomputed (reg save)
      u32 rb = rbk[i * 4 + r];
#pragma unroll
      for (int j = 0; j < 2; ++j) {
        u32 u = __float_as_uint(acc[i][j][r]) & VAL_MASK;  // v_and_or fusable
        rb = umax(rb, u | colpay[j]);
        cb[j] = umax(cb[j], u | rp);
      }
      rbk[i * 4 + r] = rb;
    }
#pragma unroll
  for (int j = 0; j < 2; ++j) {
    u32 b = cb[j];
    b = umax(b, (u32)__shfl_xor((int)b, 16, 64));
    b = umax(b, (u32)__shfl_xor((int)b, 32, 64));
    if (quad == 0) atomicMax(&colbest_tile[j * 16 + l15], b);
  }
}

// ---------- kernels ----------

// Both [256][C] f32 -> [C][256] bf16 transposes in ONE launch (each extra
// dispatch costs ~10us wall in this harness). LDS-staged: coalesced 256B
// feature-row reads, coalesced short8 stores. Also folds best-array init.
__global__ __launch_bounds__(256) void transpose_cast2(const float* __restrict__ d0,
                                                       const float* __restrict__ d1,
                                                       unsigned short* __restrict__ At,
                                                       unsigned short* __restrict__ Bt,
                                                       int N, int M,
                                                       u32* __restrict__ best, int init_n) {
  __shared__ alignas(16) unsigned short tile[64 * 132];  // 16.9 KB
  const int tid = threadIdx.x;
  const int bx = blockIdx.x;
  const int nblkA = N / 64;
  const float* src;
  unsigned short* dst;
  int C, gd0;
  if (bx < nblkA) { src = d0; dst = At; C = N; gd0 = bx * 64; }
  else           { src = d1; dst = Bt; C = M; gd0 = (bx - nblkA) * 64; }
  const int d = tid & 63;
  const int fy = blockIdx.y;  // feature half: 0 or 1
#pragma unroll
  for (int k = 0; k < 32; ++k) {
    int fl = (tid >> 6) + 4 * k;  // 0..127 within the half
    float v = src[(size_t)(fy * 128 + fl) * C + gd0 + d];
    tile[d * 132 + fl] = f2bf_rne(v);
  }
  __syncthreads();
#pragma unroll
  for (int c = 0; c < 4; ++c) {
    int slot = c * 256 + tid;
    int dd = slot >> 4, f8 = slot & 15;
    short8 o = *(const short8*)(tile + dd * 132 + f8 * 8);
    *(short8*)(dst + (size_t)(gd0 + dd) * D_DIM + fy * 128 + f8 * 8) = o;
  }
  if (fy == 0) {
    int i = bx * 256 + tid;  // 256 blocks x 256 threads >= init_n
    if (i < init_n) best[i] = 0u;
  }
}

// Full-K-in-registers GEMM + fused argmax, T3/T4-style schedule.
// 256 threads, 4 waves x 64 rows; register floor ~233 (af=128 + 2 acc banks
// 64 + rbk 16 + misc) -> 2 waves/SIMD is the ceiling. NO min-waves bound
// (R1: (256,4) -> full A spill -> 505MB scratch).
// Schedule per tile (raw s_barrier, counted vmcnt — never a full drain in
// the main loop):
//   issue stage(t+2) -> buf[(t+2)%3]          (4 gload_lds, stay in flight)
//   ds_read frags from buf[t%3]; 64 MFMA (setprio 1..0)
//   epilogue(tile t-1) from the OTHER acc bank — pure VALU, register-
//     independent of tile t's in-flight MFMAs -> matrix/VALU pipe overlap
//     (the old structure serialized: epilogue read acc -> waited MFMA done)
//   s_waitcnt vmcnt(4)  (t+1's 4 loads landed; t+2's 4 still outstanding)
//   s_barrier           (no implicit vmcnt(0)/lgkmcnt(0) drain!)
// Race audit: buf[(t+2)%3] was last read in tile t-1, and every wave's
// tile-(t-1) ds_reads complete before its barrier(t-1) (lgkm-waited before
// the MFMAs that consume them); stage(t+2) issues after that barrier. Reads
// of buf[t%3] are safe: vmcnt(4)+barrier at end of t-1 => all waves'
// stage(t) landed.
template <bool PRECAST>
__global__ __launch_bounds__(256, 1) void gemm_reduce(const float* __restrict__ A,
                                                      const unsigned short* __restrict__ At,
                                                      const unsigned short* __restrict__ Bt,
                                                      u32* __restrict__ best01,
                                                      u32* __restrict__ best10,
                                                      int N) {
  __shared__ alignas(16) unsigned short sB[3][TCOLS * D_DIM];  // 3 x 16 KB
  __shared__ u32 colbest[TILES * TCOLS];                       // 1 KB persistent col-best

  const int tid  = threadIdx.x;
  const int wave = tid >> 6;
  const int lane = tid & 63;
  const int quad = lane >> 4;
  const int l15  = lane & 15;
  const int n0   = blockIdx.x * 256;
  const int mg0  = blockIdx.y * (TILES * TCOLS);
  const int rbase = n0 + wave * 64;  // 64 rows per wave

  colbest[tid] = 0u;  // TILES*TCOLS == 256 == blockDim

  // A fragments FIRST (so the prologue vmcnt(4) drains them + stage(0)).
  short8 af[4][8];
  if constexpr (PRECAST) {
#pragma unroll
    for (int t = 0; t < 4; ++t) {
      const unsigned short* ap = At + (size_t)(rbase + t * 16 + l15) * D_DIM + quad * 8;
#pragma unroll
      for (int kc = 0; kc < 8; ++kc)
        af[t][kc] = *(const short8*)(ap + kc * 32);
    }
  } else {
#pragma unroll
    for (int t = 0; t < 4; ++t)
#pragma unroll
      for (int kc = 0; kc < 8; ++kc) {
        const int row = rbase + t * 16 + l15;
        const int kb = kc * 32 + quad * 8;
        short8 o;
#pragma unroll
        for (int u = 0; u < 8; ++u)
          o[u] = (short)f2bf_rne(A[(size_t)(kb + u) * N + row]);
        af[t][kc] = o;
      }
  }

  // stage tiles 0 and 1
  stage_tile(Bt + (size_t)mg0 * D_DIM, (unsigned short*)sB[0], tid);
  stage_tile(Bt + (size_t)(mg0 + TCOLS) * D_DIM, (unsigned short*)sB[1], tid);

  u32 rbk[16];
#pragma unroll
  for (int s = 0; s < 16; ++s) rbk[s] = 0u;
  const u32 rp0 = 0x1FFFu - (u32)(rbase + quad * 4);  // rowpay(i,r) = rp0 - 16i - r

  asm volatile("s_waitcnt vmcnt(4)" ::: "memory");  // stage(0) landed (stage(1) in flight)
  __builtin_amdgcn_s_barrier();

  floatx4 accA[4][2], accB[4][2];

#pragma unroll
  for (int mt = 0; mt < TILES; ++mt) {
    if (mt + 2 < TILES)
      stage_tile(Bt + (size_t)(mg0 + (mt + 2) * TCOLS) * D_DIM,
                 (unsigned short*)sB[(mt + 2) % 3], tid);

    floatx4 (&cur)[4][2] = (mt & 1) ? accB : accA;
    floatx4 (&prv)[4][2] = (mt & 1) ? accA : accB;
#pragma unroll
    for (int i = 0; i < 4; ++i)
#pragma unroll
      for (int j = 0; j < 2; ++j)
        cur[i][j] = (floatx4){2.0f, 2.0f, 2.0f, 2.0f};  // bias: outputs = sim+2 > 0

    const unsigned short* sb = (const unsigned short*)sB[mt % 3];
    __builtin_amdgcn_s_setprio(1);
#pragma unroll
    for (int kc = 0; kc < 8; ++kc) {
      short8 bfr[2];
#pragma unroll
      for (int j = 0; j < 2; ++j) {
        int c2 = j * 16 + l15;
        int ch = kc * 4 + quad;
        int chg = (ch & 24) | ((ch ^ c2) & 7);  // un-swizzle
        bfr[j] = *(const short8*)(sb + c2 * D_DIM + chg * 8);
      }
#pragma unroll
      for (int i = 0; i < 4; ++i)
#pragma unroll
        for (int j = 0; j < 2; ++j)
          cur[i][j] = __builtin_amdgcn_mfma_f32_16x16x32_bf16(af[i][kc], bfr[j], cur[i][j], 0, 0, 0);
    }
    __builtin_amdgcn_s_setprio(0);

    if (mt > 0)  // deferred: tile t-1's argmax, overlaps tile t's in-flight MFMAs
      epilogue(prv, mg0 + (mt - 1) * TCOLS, rbk, rp0, &colbest[(mt - 1) * TCOLS], l15, quad);

    if (mt + 1 < TILES) {
      if (mt + 2 < TILES) {
        asm volatile("s_waitcnt vmcnt(4)" ::: "memory");  // stage(mt+1) landed
      } else {
        asm volatile("s_waitcnt vmcnt(0)" ::: "memory");  // last stage: drain all
      }
      __builtin_amdgcn_s_barrier();
    }
  }

  // last tile's epilogue (TILES-1 is odd -> bank accB)
  epilogue(accB, mg0 + (TILES - 1) * TCOLS, rbk, rp0, &colbest[(TILES - 1) * TCOLS], l15, quad);

  // row-best: butterfly over l15, one global atomic per row (fire before the
  // LDS fence so the atomics overlap the wait)
#pragma unroll
  for (int i = 0; i < 4; ++i)
#pragma unroll
    for (int r = 0; r < 4; ++r) {
      u32 b = rbk[i * 4 + r];
      b = umax(b, (u32)__shfl_xor((int)b, 1, 64));
      b = umax(b, (u32)__shfl_xor((int)b, 2, 64));
      b = umax(b, (u32)__shfl_xor((int)b, 4, 64));
      b = umax(b, (u32)__shfl_xor((int)b, 8, 64));
      if (l15 == 0) atomicMax(&best01[rbase + i * 16 + quad * 4 + r], b);
    }

  // col-best flush: all waves' colbest LDS atomics done -> global
  asm volatile("s_waitcnt lgkmcnt(0)" ::: "memory");
  __builtin_amdgcn_s_barrier();
  atomicMax(&best10[mg0 + tid], colbest[tid]);
}

__global__ void finalize(const u32* __restrict__ best01, const u32* __restrict__ best10,
                         float* __restrict__ out, int N) {
  int n = blockIdx.x * blockDim.x + threadIdx.x;
  if (n >= N) return;
  u32 k = best01[n];
  int idx01 = (int)((~k) & IDX_BITS);
  float sim = __uint_as_float(k & VAL_MASK) - 2.0f;  // undo +2 bias
  int idx10 = (int)((~best10[idx01]) & IDX_BITS);
  float dist = 2.0f - 2.0f * sim;             // squared L2 for unit vectors
  bool ok = (idx10 == n) && (dist <= 0.64f);  // mutual NN + thresh^2
  out[n]     = ok ? (float)idx01 : -1.0f;
  out[N + n] = ok ? 1.5f - sim : 0.0f;        // (dist+1)/2
}

// ---------- launcher ----------

extern "C" void kernel_launch(void* const* d_in, const int* in_sizes, int n_in,
                              void* d_out, int out_size, void* d_ws, size_t ws_size,
                              hipStream_t stream) {
  (void)n_in; (void)out_size;
  const float* d0 = (const float*)d_in[0];  // [256][N]
  const float* d1 = (const float*)d_in[1];  // [256][M]
  const int N = in_sizes[0] / D_DIM;        // 8192
  const int M = in_sizes[1] / D_DIM;        // 8192

  u32* best01 = (u32*)d_ws;                          // N u32
  u32* best10 = best01 + N;                          // M u32
  unsigned short* At = (unsigned short*)(best10 + M);  // [N][256] bf16
  unsigned short* Bt = At + (size_t)N * D_DIM;         // [M][256] bf16
  float* out = (float*)d_out;

  const size_t need = (size_t)(N + M) * sizeof(u32) +
                      (size_t)(N + M) * D_DIM * sizeof(unsigned short);

  if (ws_size >= need) {
    hipLaunchKernelGGL(transpose_cast2, dim3((N + M) / 64, 2), dim3(256), 0, stream,
                       d0, d1, At, Bt, N, M, best01, N + M);
    hipLaunchKernelGGL((gemm_reduce<true>), dim3(N / 256, M / (TILES * TCOLS)), dim3(256),
                       0, stream, d0, At, Bt, best01, best10, N);
  } else {
    // ws too small for At: B-only precast, inline A cast
    unsigned short* BtF = (unsigned short*)(best10 + M);
    hipLaunchKernelGGL(transpose_cast2, dim3(M / 64, 2), dim3(256), 0, stream,
                       d1, d1, BtF, BtF, M, M, best01, N + M);
    hipLaunchKernelGGL((gemm_reduce<false>), dim3(N / 256, M / (TILES * TCOLS)), dim3(256),
                       0, stream, d0, BtF, BtF, best01, best10, N);
  }
  hipLaunchKernelGGL(finalize, dim3(N / 256), dim3(256), 0, stream, best01, best10, out, N);
}